// Round 6
// baseline (364.313 us; speedup 1.0000x reference)
//
#include <hip/hip_runtime.h>
#include <hip/hip_bf16.h>
#include <math.h>
#include <stdint.h>

#define NHEADS 32
#define HDIM 128
#define POOLW 16
#define DMODEL 1536
#define SPOOL 512
#define HDTOT 4096   // NHEADS*HDIM
#define PEROWS 1024  // 2*SPOOL
#define NPAIR (SPOOL * SPOOL)   // 262144
#define TCOLS 80     // padded table width (67 used)

typedef __hip_bfloat16 bf16;
typedef short short8 __attribute__((ext_vector_type(8)));
typedef float f32x4 __attribute__((ext_vector_type(4)));

__device__ __forceinline__ float b2f(const bf16 v) { return __bfloat162float(v); }
__device__ __forceinline__ bf16 f2b(float v) { return __float2bfloat16(v); }
__device__ __forceinline__ short f2bs(float v) {
  bf16 b = __float2bfloat16(v);
  return *reinterpret_cast<short*>(&b);
}

__device__ __forceinline__ void gload_lds16(const void* g, void* l) {
  const __attribute__((address_space(1))) uint32_t* gp =
      (const __attribute__((address_space(1))) uint32_t*)(uintptr_t)g;
  __attribute__((address_space(3))) uint32_t* lp =
      (__attribute__((address_space(3))) uint32_t*)(uintptr_t)l;
  __builtin_amdgcn_global_load_lds(gp, lp, 16, 0, 0);
}

// ---------------------------------------------------------------------------
// K1: fused pool+RMS+GELU (blocks 0..511) and W_pos suffix sums (512..527)
// ---------------------------------------------------------------------------
__global__ __launch_bounds__(256) void pool_suffix(
    const float* __restrict__ x, const float* __restrict__ w_rms,
    const float* __restrict__ W_pos,
    bf16* __restrict__ xn, bf16* __restrict__ xg,
    float* __restrict__ SW0, float* __restrict__ SW1) {
  if (blockIdx.x >= SPOOL) {
    int j = (blockIdx.x - SPOOL) * 256 + threadIdx.x;
    float s0 = 0.f, s1 = 0.f;
    SW0[32 * HDTOT + j] = 0.f;
    SW1[32 * HDTOT + j] = 0.f;
    for (int f = 31; f >= 0; --f) {
      s0 += W_pos[f * HDTOT + j];
      s1 += W_pos[(NHEADS + f) * HDTOT + j];
      SW0[f * HDTOT + j] = s0;
      SW1[f * HDTOT + j] = s1;
    }
    return;
  }
  int sp = blockIdx.x;
  int tid = threadIdx.x;
  __shared__ float buf[DMODEL];
  __shared__ float red[256];
  const float* xrow = x + (size_t)sp * POOLW * DMODEL;
  float ss = 0.f;
  for (int d = tid; d < DMODEL; d += 256) {
    float s = 0.f;
#pragma unroll
    for (int p = 0; p < POOLW; ++p) s += xrow[p * DMODEL + d];
    s *= (1.0f / POOLW);
    buf[d] = s;
    ss += s * s;
  }
  red[tid] = ss;
  __syncthreads();
  for (int off = 128; off > 0; off >>= 1) {
    if (tid < off) red[tid] += red[tid + off];
    __syncthreads();
  }
  float rms = rsqrtf(red[0] / DMODEL + 1e-6f);
  for (int d = tid; d < DMODEL; d += 256) {
    float v = buf[d] * rms * w_rms[d];
    xn[(size_t)sp * DMODEL + d] = f2b(v);
    xg[(size_t)sp * DMODEL + d] = f2b(0.5f * v * (1.0f + erff(v * 0.70710678118654752f)));
  }
}

// ---------------------------------------------------------------------------
// K2b: prep. blocks 0..31: SWb[h][g][c] bf16 (g<33:SW0, 33..65:SW1, 66:b_pos, pad 0)
//      blocks 32..95: RB[s*32+h][g] = rbias . SWcat  (g>=67 -> 0)
//      block 96: fm table (1024 entries); block 97: WpT transpose
// ---------------------------------------------------------------------------
__global__ __launch_bounds__(256) void prep_kernel(
    const float* __restrict__ SW0, const float* __restrict__ SW1,
    const float* __restrict__ b_pos, const float* __restrict__ qrb,
    const float* __restrict__ krb, const float* __restrict__ W_pair,
    bf16* __restrict__ SWb, float* __restrict__ RB, short* __restrict__ fm_tab,
    bf16* __restrict__ WpT) {
  int b = blockIdx.x, t = threadIdx.x;
  if (b < 32) {
    int h = b;
    bf16* dst = SWb + (size_t)h * 128 * 128;
    for (int rr = 0; rr < 128; rr += 2) {
      int g = rr + (t >> 7);
      int c = t & 127;
      float v;
      if (g < 33) v = SW0[(size_t)g * HDTOT + h * 128 + c];
      else if (g < 66) v = SW1[(size_t)(g - 33) * HDTOT + h * 128 + c];
      else if (g == 66) v = b_pos[h * 128 + c];
      else v = 0.f;
      dst[(size_t)g * 128 + c] = f2b(v);
    }
  } else if (b < 96) {
    int idx = b - 32;           // s*32 + h
    int s = idx >> 5, h = idx & 31;
    const float* rb = (s ? krb : qrb) + h * 128;
    if (t < 128) {
      int g = t;
      float acc = 0.f;
      if (g < 33) { for (int c = 0; c < 128; ++c) acc += rb[c] * SW0[(size_t)g * HDTOT + h * 128 + c]; }
      else if (g < 66) { for (int c = 0; c < 128; ++c) acc += rb[c] * SW1[(size_t)(g - 33) * HDTOT + h * 128 + c]; }
      else if (g == 66) { for (int c = 0; c < 128; ++c) acc += rb[c] * b_pos[h * 128 + c]; }
      RB[(size_t)idx * 128 + g] = acc;
    }
  } else if (b == 96) {
    for (int p = t; p < 1024; p += 256) {
      float dist = fabsf((float)(p - 512));
      double ls = log(481.0) / 32.0;  // log(512-32+1)/32
      int fmv = 0;
      for (int f = 0; f < 32; ++f) {
        float cw = (float)f + expf((float)f * (float)ls);
        if (cw <= dist) fmv = f + 1;
      }
      fm_tab[p] = (short)fmv;
    }
  } else {
    for (int idx = t; idx < NHEADS * HDIM; idx += 256) {
      int c = idx >> 5, h = idx & 31;
      WpT[(size_t)c * 32 + h] = f2b(W_pair[h * HDIM + c]);
    }
  }
}

// ---------------------------------------------------------------------------
// K5a: projection GEMM, N-slab 32, M-tile 256, grid (264, 2).
//  bx<256: C=QKp bf16, A=xn, W = W_q|W_k (ldw 4096)
//  bx>=256: C=yqk f32, A=xg, W = W_yq|W_yk (ldw 128)
// W read directly in f32 [K][N]: each block reads its 32-col W slab once
// (196 KB), reused across the K loop -> W HBM traffic ~2x unique (by=2).
// ---------------------------------------------------------------------------
__global__ __launch_bounds__(256) void gemm_proj32(
    const bf16* __restrict__ xn, const bf16* __restrict__ xg,
    const float* __restrict__ W_q, const float* __restrict__ W_k,
    const float* __restrict__ W_yq, const float* __restrict__ W_yk,
    bf16* __restrict__ QKp, float* __restrict__ yqk) {
  __shared__ short Asub[256][32];
  __shared__ short Bsub[32][40];
  const int t = threadIdx.x;
  const int lane = t & 63, w = t >> 6;
  const int quad = lane >> 4, mr = lane & 15;
  const int bx = blockIdx.x;
  const int m0 = blockIdx.y * 256;
  const int wm = w * 64;

  const bf16* A;
  const float* Wb;
  int ncol, ldw;
  if (bx < 256) {
    A = xn;
    int n0 = bx * 32;
    if (n0 < 4096) { Wb = W_q; ncol = n0; } else { Wb = W_k; ncol = n0 - 4096; }
    ldw = 4096;
  } else {
    A = xg;
    int n0 = (bx - 256) * 32;
    if (n0 < 128) { Wb = W_yq; ncol = n0; } else { Wb = W_yk; ncol = n0 - 128; }
    ldw = 128;
  }

  int a_r[4], a_c[4];
#pragma unroll
  for (int j = 0; j < 4; ++j) {
    int c = t + j * 256;
    int r = c >> 2, pc = c & 3;
    a_r[j] = r;
    a_c[j] = (pc ^ (r & 3)) * 8;
  }
  const int kr = t >> 3, nq = t & 7;

  f32x4 acc[4][2];
#pragma unroll
  for (int mi = 0; mi < 4; ++mi)
#pragma unroll
    for (int ni = 0; ni < 2; ++ni) acc[mi][ni] = (f32x4){0.f, 0.f, 0.f, 0.f};

  for (int k0 = 0; k0 < DMODEL; k0 += 32) {
#pragma unroll
    for (int j = 0; j < 4; ++j)
      gload_lds16(A + (size_t)(m0 + a_r[j]) * DMODEL + k0 + a_c[j],
                  (char*)&Asub[0][0] + (size_t)(t + j * 256) * 16);
    {
      f32x4 wv = *(const f32x4*)&Wb[(size_t)(k0 + kr) * ldw + ncol + nq * 4];
      Bsub[nq * 4 + 0][kr] = f2bs(wv[0]);
      Bsub[nq * 4 + 1][kr] = f2bs(wv[1]);
      Bsub[nq * 4 + 2][kr] = f2bs(wv[2]);
      Bsub[nq * 4 + 3][kr] = f2bs(wv[3]);
    }
    __syncthreads();
    short8 af[4];
#pragma unroll
    for (int mi = 0; mi < 4; ++mi) {
      int r = wm + mi * 16 + mr;
      af[mi] = *(const short8*)&Asub[r][(quad ^ (r & 3)) * 8];
    }
    short8 bfr[2];
#pragma unroll
    for (int ni = 0; ni < 2; ++ni) {
      int rb = ni * 16 + mr;
      bfr[ni] = *(const short8*)&Bsub[rb][quad * 8];
    }
#pragma unroll
    for (int mi = 0; mi < 4; ++mi)
#pragma unroll
      for (int ni = 0; ni < 2; ++ni)
        acc[mi][ni] = __builtin_amdgcn_mfma_f32_16x16x32_bf16(af[mi], bfr[ni], acc[mi][ni], 0, 0, 0);
    __syncthreads();
  }

#pragma unroll
  for (int mi = 0; mi < 4; ++mi) {
#pragma unroll
    for (int ni = 0; ni < 2; ++ni) {
#pragma unroll
      for (int r = 0; r < 4; ++r) {
        int gm = m0 + wm + mi * 16 + quad * 4 + r;
        int gnl = ni * 16 + mr;
        float v = acc[mi][ni][r];
        if (bx < 256) {
          QKp[(size_t)gm * 8192 + bx * 32 + gnl] = f2b(v);
        } else {
          yqk[(size_t)gm * 256 + (bx - 256) * 32 + gnl] = v;
        }
      }
    }
  }
}

// ---------------------------------------------------------------------------
// K5b: table GEMM (bf16 B via global_load_lds):
//  z = side*32 + h. A = QKp + side*4096 + h*128 (lda 8192). B = SWb[h].
//  C = Tg + z*512*TCOLS (f32), store gn<TCOLS with RB[z][gn] added.
// ---------------------------------------------------------------------------
__global__ __launch_bounds__(256) void gemm_table(
    const bf16* __restrict__ QKp, const bf16* __restrict__ SWb,
    const float* __restrict__ RB, float* __restrict__ Tg) {
  __shared__ short Asub[128][32];
  __shared__ short Bsub[64][32];
  const int t = threadIdx.x;
  const int lane = t & 63;
  const int w = t >> 6;
  const int z = blockIdx.z;
  const int m0 = blockIdx.y * 128, n0 = blockIdx.x * 64;
  const int wm = (w >> 1) * 64, wn = (w & 1) * 32;
  const bf16* Ag = QKp + (size_t)(z >> 5) * 4096 + (size_t)(z & 31) * 128;
  const bf16* Bg = SWb + (size_t)(z & 31) * 128 * 128;

  const int ar0 = t >> 2;
  const int as0 = t & 3;
  const int ao0 = as0 ^ (ar0 & 3);
  char* AsubB = (char*)&Asub[0][0];
  char* BsubB = (char*)&Bsub[0][0];
  char* ldsA0 = AsubB + w * 1024;
  char* ldsA1 = AsubB + 4096 + w * 1024;
  char* ldsB0 = BsubB + w * 1024;

  const int quad = lane >> 4, mr = lane & 15;
  f32x4 acc[4][2];
#pragma unroll
  for (int mi = 0; mi < 4; ++mi)
#pragma unroll
    for (int ni = 0; ni < 2; ++ni) acc[mi][ni] = (f32x4){0.f, 0.f, 0.f, 0.f};

  for (int k0 = 0; k0 < 128; k0 += 32) {
    gload_lds16(Ag + (size_t)(m0 + ar0) * 8192 + k0 + ao0 * 8, ldsA0);
    gload_lds16(Ag + (size_t)(m0 + 64 + ar0) * 8192 + k0 + ao0 * 8, ldsA1);
    gload_lds16(Bg + (size_t)(n0 + ar0) * 128 + k0 + ao0 * 8, ldsB0);
    __syncthreads();
    short8 af[4];
#pragma unroll
    for (int mi = 0; mi < 4; ++mi) {
      int r = wm + mi * 16 + mr;
      af[mi] = *(const short8*)&Asub[r][(quad ^ (r & 3)) * 8];
    }
    short8 bfr[2];
#pragma unroll
    for (int ni = 0; ni < 2; ++ni) {
      int r = wn + ni * 16 + mr;
      bfr[ni] = *(const short8*)&Bsub[r][(quad ^ (r & 3)) * 8];
    }
#pragma unroll
    for (int mi = 0; mi < 4; ++mi)
#pragma unroll
      for (int ni = 0; ni < 2; ++ni)
        acc[mi][ni] = __builtin_amdgcn_mfma_f32_16x16x32_bf16(af[mi], bfr[ni], acc[mi][ni], 0, 0, 0);
    __syncthreads();
  }

  float* Cz = Tg + (size_t)z * 512 * TCOLS;
  const float* ex = RB + (size_t)z * 128;
#pragma unroll
  for (int mi = 0; mi < 4; ++mi) {
#pragma unroll
    for (int ni = 0; ni < 2; ++ni) {
#pragma unroll
      for (int r = 0; r < 4; ++r) {
        int gm = m0 + wm + mi * 16 + quad * 4 + r;
        int gn = n0 + wn + ni * 16 + mr;
        if (gn < TCOLS) Cz[(size_t)gm * TCOLS + gn] = acc[mi][ni][r] + ex[gn];
      }
    }
  }
}

// ---------------------------------------------------------------------------
// MEGA: per 32x32 (q,k) tile, loop h: waves 0-3 compute S (MFMA) while waves
// 4-7 stage h+1 (QK dbuf + T dbuf); then all 512 threads pack column h of P.
// Epilogue: pair projection + bias/yq/yk adds -> out.
// LDS (bytes): Qs dbuf @0 (2x8192), Ks dbuf @16384, Tq dbuf @32768 (2x10240),
//   Tk dbuf @53248, Ssc @73728 (32x33 f32), fmL @77952 (1024 s), Pl @80000
//   (1024x40 s). total 161920.
// ---------------------------------------------------------------------------
#define MEGA_LDS 161920
__global__ __launch_bounds__(512) void mega_kernel(
    const bf16* __restrict__ QKp, const float* __restrict__ Tg,
    const short* __restrict__ fm_tab, const bf16* __restrict__ WpT,
    const float* __restrict__ b_pair, const float* __restrict__ yqk,
    float* __restrict__ out) {
  extern __shared__ char sm[];
  float* Ssc = (float*)(sm + 73728);
  short* fmL = (short*)(sm + 77952);
  short* Pl = (short*)(sm + 80000);

  const int t = threadIdx.x;
  const int lane = t & 63, w = t >> 6;
  const int quad = lane >> 4, mr = lane & 15;
  const int q0 = (blockIdx.x >> 4) * 32;
  const int k0 = (blockIdx.x & 15) * 32;

  // staging constants (waves 4-7)
  const int ttc = (t >= 256) ? (t - 256) : 0;
  int qk_r[2], qk_c[2];
#pragma unroll
  for (int j = 0; j < 2; ++j) {
    int c = ttc + j * 256;          // 0..511
    int ks = c >> 7, cc = c & 127;
    int r = cc >> 2, pc = cc & 3;
    qk_r[j] = r;
    qk_c[j] = ks * 32 + ((pc ^ (r & 3)) * 8);
  }
  const int t_n = (t >= 256 && ttc < 128) ? 3 : 2;   // wave-uniform
  int t_row[3], t_off[3];
#pragma unroll
  for (int j = 0; j < 3; ++j) {
    int c = ttc + j * 256;          // 0..639
    t_row[j] = c / 20;
    t_off[j] = (c - t_row[j] * 20) * 4;
  }

#define STAGE_ALL(hh)                                                                  \
  {                                                                                    \
    int bsel = (hh) & 1;                                                               \
    char* qdst = sm + bsel * 8192;                                                     \
    char* kdst = sm + 16384 + bsel * 8192;                                             \
    char* tqdst = sm + 32768 + bsel * 10240;                                           \
    char* tkdst = sm + 53248 + bsel * 10240;                                           \
    const float* sq_ = Tg + (size_t)(hh)*512 * TCOLS;                                  \
    const float* sk_ = Tg + (size_t)(32 + (hh)) * 512 * TCOLS;                         \
    _Pragma("unroll")                                                                  \
    for (int j = 0; j < 2; ++j) {                                                      \
      int c = ttc + j * 256;                                                           \
      gload_lds16(QKp + (size_t)(q0 + qk_r[j]) * 8192 + (hh)*128 + qk_c[j],            \
                  qdst + (size_t)c * 16);                                              \
      gload_lds16(QKp + (size_t)(k0 + qk_r[j]) * 8192 + 4096 + (hh)*128 + qk_c[j],     \
                  kdst + (size_t)c * 16);                                              \
    }                                                                                  \
    for (int j = 0; j < t_n; ++j) {                                                    \
      int c = ttc + j * 256;                                                           \
      gload_lds16(sq_ + (size_t)(q0 + t_row[j]) * TCOLS + t_off[j],                    \
                  tqdst + (size_t)c * 16);                                             \
      gload_lds16(sk_ + (size_t)(k0 + t_row[j]) * TCOLS + t_off[j],                    \
                  tkdst + (size_t)c * 16);                                             \
    }                                                                                  \
  }

  // prologue: waves 4-7 stage h=0; waves 0-1 stage fm table
  if (t < 128) gload_lds16(fm_tab + t * 8, (char*)fmL + t * 16);
  if (t >= 256) STAGE_ALL(0);
  __syncthreads();

  // hoist h-invariant pack indices
  int tqa[2], tqb[2], tqc[2], tka[2], tkb[2], tkc[2], ssco[2], plo[2];
  float sgn[2];
#pragma unroll
  for (int j = 0; j < 2; ++j) {
    int m = j * 512 + t;
    int qL = m >> 5, kL = m & 31;
    int pq = 512 + (k0 + kL) - (q0 + qL);
    int gq = fmL[pq], gk = fmL[1024 - pq];
    sgn[j] = (pq > 512) ? 1.f : ((pq < 512) ? -1.f : 0.f);
    tqa[j] = qL * TCOLS + gq;
    tqb[j] = qL * TCOLS + 33 + gq;
    tqc[j] = qL * TCOLS + 66;
    tka[j] = kL * TCOLS + gk;
    tkb[j] = kL * TCOLS + 33 + gk;
    tkc[j] = kL * TCOLS + 66;
    ssco[j] = qL * 33 + kL;
    plo[j] = m * 40;
  }

  for (int h = 0; h < 32; ++h) {
    // ---- phase A: waves 0-3 compute S(h); waves 4-7 stage h+1 ----
    if (w < 4) {
      const short* Qb = (const short*)(sm + (h & 1) * 8192);
      const short* Kb = (const short*)(sm + 16384 + (h & 1) * 8192);
      const int smi = w >> 1, sni = w & 1;
      const int ra = smi * 16 + mr, rb = sni * 16 + mr;
      f32x4 accS = (f32x4){0.f, 0.f, 0.f, 0.f};
#pragma unroll
      for (int ks = 0; ks < 4; ++ks) {
        short8 af = *(const short8*)&Qb[ks * 1024 + ra * 32 + ((quad ^ (ra & 3)) * 8)];
        short8 bfv = *(const short8*)&Kb[ks * 1024 + rb * 32 + ((quad ^ (rb & 3)) * 8)];
        accS = __builtin_amdgcn_mfma_f32_16x16x32_bf16(af, bfv, accS, 0, 0, 0);
      }
#pragma unroll
      for (int r = 0; r < 4; ++r)
        Ssc[(smi * 16 + quad * 4 + r) * 33 + sni * 16 + mr] = accS[r];
    } else if (h < 31) {
      STAGE_ALL(h + 1);
    }
    __syncthreads();
    // ---- phase B: pack column h of P ----
    {
      const float* tq = (const float*)(sm + 32768 + (h & 1) * 10240);
      const float* tk = (const float*)(sm + 53248 + (h & 1) * 10240);
#pragma unroll
      for (int j = 0; j < 2; ++j) {
        float vq = tq[tqa[j]] + sgn[j] * tq[tqb[j]] + tq[tqc[j]];
        float vk = tk[tka[j]] - sgn[j] * tk[tkb[j]] + tk[tkc[j]];
        float val = Ssc[ssco[j]] + 0.5f * (vq + vk);
        Pl[plo[j] + h] = f2bs(val);
      }
    }
    __syncthreads();
  }

  // ---- pair projection + epilogue ----
  short8 bfr[8];
  float bp[8];
#pragma unroll
  for (int ni = 0; ni < 8; ++ni) {
    int c = ni * 16 + mr;
    bfr[ni] = *(const short8*)(WpT + (size_t)c * 32 + quad * 8);
    bp[ni] = b_pair[c];
  }
#pragma unroll
  for (int mi = 0; mi < 8; ++mi) {
    int mb = w * 128 + mi * 16;
    short8 af = *(const short8*)&Pl[(mb + mr) * 40 + quad * 8];
    f32x4 acc[8];
#pragma unroll
    for (int ni = 0; ni < 8; ++ni)
      acc[ni] = __builtin_amdgcn_mfma_f32_16x16x32_bf16(
          af, bfr[ni], (f32x4){0.f, 0.f, 0.f, 0.f}, 0, 0, 0);
#pragma unroll
    for (int r = 0; r < 4; ++r) {
      int m = mb + quad * 4 + r;
      int q = q0 + (m >> 5), k = k0 + (m & 31);
      const float* yq = yqk + (size_t)q * 256;
      const float* yk = yqk + (size_t)k * 256 + 128;
      float* orow = out + ((size_t)q * 512 + k) * 128;
#pragma unroll
      for (int ni = 0; ni < 8; ++ni) {
        int c = ni * 16 + mr;
        orow[c] = acc[ni][r] + bp[ni] + yq[c] + yk[c];
      }
    }
  }
}

// ===========================================================================
extern "C" void kernel_launch(void* const* d_in, const int* in_sizes, int n_in,
                              void* d_out, int out_size, void* d_ws, size_t ws_size,
                              hipStream_t stream) {
  const float* x      = (const float*)d_in[0];
  const float* w_rms  = (const float*)d_in[1];
  const float* W_q    = (const float*)d_in[2];
  const float* W_k    = (const float*)d_in[3];
  const float* W_pos  = (const float*)d_in[4];
  const float* b_pos  = (const float*)d_in[5];
  const float* qrb    = (const float*)d_in[6];
  const float* krb    = (const float*)d_in[7];
  const float* W_yq   = (const float*)d_in[8];
  const float* W_yk   = (const float*)d_in[9];
  const float* W_pair = (const float*)d_in[10];
  const float* b_pair = (const float*)d_in[11];
  float* out = (float*)d_out;

  static bool attr_set = false;
  if (!attr_set) {
    (void)hipFuncSetAttribute((const void*)mega_kernel,
                              hipFuncAttributeMaxDynamicSharedMemorySize, MEGA_LDS);
    attr_set = true;
  }

  // ---- workspace layout (~42 MB) ----
  char* w = (char*)d_ws;
  bf16* xn   = (bf16*)w; w += (size_t)SPOOL * DMODEL * 2;       // 1.5 MB
  bf16* xg   = (bf16*)w; w += (size_t)SPOOL * DMODEL * 2;       // 1.5 MB
  bf16* QKp  = (bf16*)w; w += (size_t)SPOOL * 8192 * 2;         // 8.4 MB (Q|K)
  float* yqk = (float*)w; w += (size_t)SPOOL * 256 * 4;         // 0.5 MB
  bf16* WpT  = (bf16*)w; w += (size_t)HDIM * NHEADS * 2;        // 8 KB
  float* SW0 = (float*)w; w += (size_t)33 * HDTOT * 4;          // 0.54 MB
  float* SW1 = (float*)w; w += (size_t)33 * HDTOT * 4;          // 0.54 MB
  bf16* SWb  = (bf16*)w; w += (size_t)NHEADS * 128 * 128 * 2;   // 1.05 MB
  float* RB  = (float*)w; w += (size_t)64 * 128 * 4;            // 32 KB
  short* fm_tab = (short*)w; w += 1024 * 2;                     // 2 KB
  w = (char*)(((uintptr_t)w + 255) & ~(uintptr_t)255);
  float* Tg = (float*)w; w += (size_t)2 * NHEADS * SPOOL * TCOLS * 4;  // 26.2 MB

  // 1. fused pool+rms+gelu (blocks 0..511) + suffix sums (512..527)
  pool_suffix<<<SPOOL + HDTOT / 256, 256, 0, stream>>>(x, w_rms, W_pos, xn, xg, SW0, SW1);
  // 2. prep tables (SWb, RB, fm, WpT)
  prep_kernel<<<98, 256, 0, stream>>>(SW0, SW1, b_pos, qrb, krb, W_pair,
                                      SWb, RB, fm_tab, WpT);
  // 3. merged projections: Q|K (bf16) + yq|yk (f32), W read directly (f32)
  gemm_proj32<<<dim3(264, 2), 256, 0, stream>>>(
      xn, xg, W_q, W_k, W_yq, W_yk, QKp, yqk);
  // 4. rel tables (both sides, z = side*32+h)
  gemm_table<<<dim3(128 / 64, SPOOL / 128, 64), 256, 0, stream>>>(QKp, SWb, RB, Tg);
  // 5. fused S + rel-lookup + pack + pair projection + epilogue
  mega_kernel<<<256, 512, MEGA_LDS, stream>>>(QKp, Tg, fm_tab, WpT, b_pair, yqk, out);
}

// Round 7
// 350.492 us; speedup vs baseline: 1.0394x; 1.0394x over previous
//
#include <hip/hip_runtime.h>
#include <hip/hip_bf16.h>
#include <math.h>
#include <stdint.h>

#define NHEADS 32
#define HDIM 128
#define POOLW 16
#define DMODEL 1536
#define SPOOL 512
#define HDTOT 4096   // NHEADS*HDIM
#define PEROWS 1024  // 2*SPOOL
#define NPAIR (SPOOL * SPOOL)   // 262144
#define TCOLS 80     // table width in GLOBAL memory (67 used)
#define TLDS 84      // table row stride in LDS (bank-spread: 84%32=20 -> 8 banks)

typedef __hip_bfloat16 bf16;
typedef short short8 __attribute__((ext_vector_type(8)));
typedef float f32x4 __attribute__((ext_vector_type(4)));

__device__ __forceinline__ float b2f(const bf16 v) { return __bfloat162float(v); }
__device__ __forceinline__ bf16 f2b(float v) { return __float2bfloat16(v); }
__device__ __forceinline__ short f2bs(float v) {
  bf16 b = __float2bfloat16(v);
  return *reinterpret_cast<short*>(&b);
}

__device__ __forceinline__ void gload_lds16(const void* g, void* l) {
  const __attribute__((address_space(1))) uint32_t* gp =
      (const __attribute__((address_space(1))) uint32_t*)(uintptr_t)g;
  __attribute__((address_space(3))) uint32_t* lp =
      (__attribute__((address_space(3))) uint32_t*)(uintptr_t)l;
  __builtin_amdgcn_global_load_lds(gp, lp, 16, 0, 0);
}

// ---------------------------------------------------------------------------
// K1: fused pool+RMS+GELU (blocks 0..511) and W_pos suffix sums (512..527)
// ---------------------------------------------------------------------------
__global__ __launch_bounds__(256) void pool_suffix(
    const float* __restrict__ x, const float* __restrict__ w_rms,
    const float* __restrict__ W_pos,
    bf16* __restrict__ xn, bf16* __restrict__ xg,
    float* __restrict__ SW0, float* __restrict__ SW1) {
  if (blockIdx.x >= SPOOL) {
    int j = (blockIdx.x - SPOOL) * 256 + threadIdx.x;
    float s0 = 0.f, s1 = 0.f;
    SW0[32 * HDTOT + j] = 0.f;
    SW1[32 * HDTOT + j] = 0.f;
    for (int f = 31; f >= 0; --f) {
      s0 += W_pos[f * HDTOT + j];
      s1 += W_pos[(NHEADS + f) * HDTOT + j];
      SW0[f * HDTOT + j] = s0;
      SW1[f * HDTOT + j] = s1;
    }
    return;
  }
  int sp = blockIdx.x;
  int tid = threadIdx.x;
  __shared__ float buf[DMODEL];
  __shared__ float red[256];
  const float* xrow = x + (size_t)sp * POOLW * DMODEL;
  float ss = 0.f;
  for (int d = tid; d < DMODEL; d += 256) {
    float s = 0.f;
#pragma unroll
    for (int p = 0; p < POOLW; ++p) s += xrow[p * DMODEL + d];
    s *= (1.0f / POOLW);
    buf[d] = s;
    ss += s * s;
  }
  red[tid] = ss;
  __syncthreads();
  for (int off = 128; off > 0; off >>= 1) {
    if (tid < off) red[tid] += red[tid + off];
    __syncthreads();
  }
  float rms = rsqrtf(red[0] / DMODEL + 1e-6f);
  for (int d = tid; d < DMODEL; d += 256) {
    float v = buf[d] * rms * w_rms[d];
    xn[(size_t)sp * DMODEL + d] = f2b(v);
    xg[(size_t)sp * DMODEL + d] = f2b(0.5f * v * (1.0f + erff(v * 0.70710678118654752f)));
  }
}

// ---------------------------------------------------------------------------
// K2b: prep. blocks 0..31: SWb[h][g][c] bf16 (g<33:SW0, 33..65:SW1, 66:b_pos, pad 0)
//      blocks 32..95: RB[s*32+h][g] = rbias . SWcat  (g>=67 -> 0)
//      block 96: fm table (1024 entries); block 97: WpT transpose
// ---------------------------------------------------------------------------
__global__ __launch_bounds__(256) void prep_kernel(
    const float* __restrict__ SW0, const float* __restrict__ SW1,
    const float* __restrict__ b_pos, const float* __restrict__ qrb,
    const float* __restrict__ krb, const float* __restrict__ W_pair,
    bf16* __restrict__ SWb, float* __restrict__ RB, short* __restrict__ fm_tab,
    bf16* __restrict__ WpT) {
  int b = blockIdx.x, t = threadIdx.x;
  if (b < 32) {
    int h = b;
    bf16* dst = SWb + (size_t)h * 128 * 128;
    for (int rr = 0; rr < 128; rr += 2) {
      int g = rr + (t >> 7);
      int c = t & 127;
      float v;
      if (g < 33) v = SW0[(size_t)g * HDTOT + h * 128 + c];
      else if (g < 66) v = SW1[(size_t)(g - 33) * HDTOT + h * 128 + c];
      else if (g == 66) v = b_pos[h * 128 + c];
      else v = 0.f;
      dst[(size_t)g * 128 + c] = f2b(v);
    }
  } else if (b < 96) {
    int idx = b - 32;           // s*32 + h
    int s = idx >> 5, h = idx & 31;
    const float* rb = (s ? krb : qrb) + h * 128;
    if (t < 128) {
      int g = t;
      float acc = 0.f;
      if (g < 33) { for (int c = 0; c < 128; ++c) acc += rb[c] * SW0[(size_t)g * HDTOT + h * 128 + c]; }
      else if (g < 66) { for (int c = 0; c < 128; ++c) acc += rb[c] * SW1[(size_t)(g - 33) * HDTOT + h * 128 + c]; }
      else if (g == 66) { for (int c = 0; c < 128; ++c) acc += rb[c] * b_pos[h * 128 + c]; }
      RB[(size_t)idx * 128 + g] = acc;
    }
  } else if (b == 96) {
    for (int p = t; p < 1024; p += 256) {
      float dist = fabsf((float)(p - 512));
      double ls = log(481.0) / 32.0;  // log(512-32+1)/32
      int fmv = 0;
      for (int f = 0; f < 32; ++f) {
        float cw = (float)f + expf((float)f * (float)ls);
        if (cw <= dist) fmv = f + 1;
      }
      fm_tab[p] = (short)fmv;
    }
  } else {
    for (int idx = t; idx < NHEADS * HDIM; idx += 256) {
      int c = idx >> 5, h = idx & 31;
      WpT[(size_t)c * 32 + h] = f2b(W_pair[h * HDIM + c]);
    }
  }
}

// ---------------------------------------------------------------------------
// K5a: projection GEMM, N-slab 32, M-tile 256, grid (264, 2).
//  bx<256: C=QKp bf16, A=xn, W = W_q|W_k (ldw 4096)
//  bx>=256: C=yqk f32, A=xg, W = W_yq|W_yk (ldw 128)
// ---------------------------------------------------------------------------
__global__ __launch_bounds__(256) void gemm_proj32(
    const bf16* __restrict__ xn, const bf16* __restrict__ xg,
    const float* __restrict__ W_q, const float* __restrict__ W_k,
    const float* __restrict__ W_yq, const float* __restrict__ W_yk,
    bf16* __restrict__ QKp, float* __restrict__ yqk) {
  __shared__ short Asub[256][32];
  __shared__ short Bsub[32][40];
  const int t = threadIdx.x;
  const int lane = t & 63, w = t >> 6;
  const int quad = lane >> 4, mr = lane & 15;
  const int bx = blockIdx.x;
  const int m0 = blockIdx.y * 256;
  const int wm = w * 64;

  const bf16* A;
  const float* Wb;
  int ncol, ldw;
  if (bx < 256) {
    A = xn;
    int n0 = bx * 32;
    if (n0 < 4096) { Wb = W_q; ncol = n0; } else { Wb = W_k; ncol = n0 - 4096; }
    ldw = 4096;
  } else {
    A = xg;
    int n0 = (bx - 256) * 32;
    if (n0 < 128) { Wb = W_yq; ncol = n0; } else { Wb = W_yk; ncol = n0 - 128; }
    ldw = 128;
  }

  int a_r[4], a_c[4];
#pragma unroll
  for (int j = 0; j < 4; ++j) {
    int c = t + j * 256;
    int r = c >> 2, pc = c & 3;
    a_r[j] = r;
    a_c[j] = (pc ^ (r & 3)) * 8;
  }
  const int kr = t >> 3, nq = t & 7;

  f32x4 acc[4][2];
#pragma unroll
  for (int mi = 0; mi < 4; ++mi)
#pragma unroll
    for (int ni = 0; ni < 2; ++ni) acc[mi][ni] = (f32x4){0.f, 0.f, 0.f, 0.f};

  for (int k0 = 0; k0 < DMODEL; k0 += 32) {
#pragma unroll
    for (int j = 0; j < 4; ++j)
      gload_lds16(A + (size_t)(m0 + a_r[j]) * DMODEL + k0 + a_c[j],
                  (char*)&Asub[0][0] + (size_t)(t + j * 256) * 16);
    {
      f32x4 wv = *(const f32x4*)&Wb[(size_t)(k0 + kr) * ldw + ncol + nq * 4];
      Bsub[nq * 4 + 0][kr] = f2bs(wv[0]);
      Bsub[nq * 4 + 1][kr] = f2bs(wv[1]);
      Bsub[nq * 4 + 2][kr] = f2bs(wv[2]);
      Bsub[nq * 4 + 3][kr] = f2bs(wv[3]);
    }
    __syncthreads();
    short8 af[4];
#pragma unroll
    for (int mi = 0; mi < 4; ++mi) {
      int r = wm + mi * 16 + mr;
      af[mi] = *(const short8*)&Asub[r][(quad ^ (r & 3)) * 8];
    }
    short8 bfr[2];
#pragma unroll
    for (int ni = 0; ni < 2; ++ni) {
      int rb = ni * 16 + mr;
      bfr[ni] = *(const short8*)&Bsub[rb][quad * 8];
    }
#pragma unroll
    for (int mi = 0; mi < 4; ++mi)
#pragma unroll
      for (int ni = 0; ni < 2; ++ni)
        acc[mi][ni] = __builtin_amdgcn_mfma_f32_16x16x32_bf16(af[mi], bfr[ni], acc[mi][ni], 0, 0, 0);
    __syncthreads();
  }

#pragma unroll
  for (int mi = 0; mi < 4; ++mi) {
#pragma unroll
    for (int ni = 0; ni < 2; ++ni) {
#pragma unroll
      for (int r = 0; r < 4; ++r) {
        int gm = m0 + wm + mi * 16 + quad * 4 + r;
        int gnl = ni * 16 + mr;
        float v = acc[mi][ni][r];
        if (bx < 256) {
          QKp[(size_t)gm * 8192 + bx * 32 + gnl] = f2b(v);
        } else {
          yqk[(size_t)gm * 256 + (bx - 256) * 32 + gnl] = v;
        }
      }
    }
  }
}

// ---------------------------------------------------------------------------
// K5b: table GEMM (bf16 B via global_load_lds):
//  z = side*32 + h. A = QKp + side*4096 + h*128 (lda 8192). B = SWb[h].
//  C = Tg + z*512*TCOLS (f32), store gn<TCOLS with RB[z][gn] added.
// ---------------------------------------------------------------------------
__global__ __launch_bounds__(256) void gemm_table(
    const bf16* __restrict__ QKp, const bf16* __restrict__ SWb,
    const float* __restrict__ RB, float* __restrict__ Tg) {
  __shared__ short Asub[128][32];
  __shared__ short Bsub[64][32];
  const int t = threadIdx.x;
  const int lane = t & 63;
  const int w = t >> 6;
  const int z = blockIdx.z;
  const int m0 = blockIdx.y * 128, n0 = blockIdx.x * 64;
  const int wm = (w >> 1) * 64, wn = (w & 1) * 32;
  const bf16* Ag = QKp + (size_t)(z >> 5) * 4096 + (size_t)(z & 31) * 128;
  const bf16* Bg = SWb + (size_t)(z & 31) * 128 * 128;

  const int ar0 = t >> 2;
  const int as0 = t & 3;
  const int ao0 = as0 ^ (ar0 & 3);
  char* AsubB = (char*)&Asub[0][0];
  char* BsubB = (char*)&Bsub[0][0];
  char* ldsA0 = AsubB + w * 1024;
  char* ldsA1 = AsubB + 4096 + w * 1024;
  char* ldsB0 = BsubB + w * 1024;

  const int quad = lane >> 4, mr = lane & 15;
  f32x4 acc[4][2];
#pragma unroll
  for (int mi = 0; mi < 4; ++mi)
#pragma unroll
    for (int ni = 0; ni < 2; ++ni) acc[mi][ni] = (f32x4){0.f, 0.f, 0.f, 0.f};

  for (int k0 = 0; k0 < 128; k0 += 32) {
    gload_lds16(Ag + (size_t)(m0 + ar0) * 8192 + k0 + ao0 * 8, ldsA0);
    gload_lds16(Ag + (size_t)(m0 + 64 + ar0) * 8192 + k0 + ao0 * 8, ldsA1);
    gload_lds16(Bg + (size_t)(n0 + ar0) * 128 + k0 + ao0 * 8, ldsB0);
    __syncthreads();
    short8 af[4];
#pragma unroll
    for (int mi = 0; mi < 4; ++mi) {
      int r = wm + mi * 16 + mr;
      af[mi] = *(const short8*)&Asub[r][(quad ^ (r & 3)) * 8];
    }
    short8 bfr[2];
#pragma unroll
    for (int ni = 0; ni < 2; ++ni) {
      int r = wn + ni * 16 + mr;
      bfr[ni] = *(const short8*)&Bsub[r][(quad ^ (r & 3)) * 8];
    }
#pragma unroll
    for (int mi = 0; mi < 4; ++mi)
#pragma unroll
      for (int ni = 0; ni < 2; ++ni)
        acc[mi][ni] = __builtin_amdgcn_mfma_f32_16x16x32_bf16(af[mi], bfr[ni], acc[mi][ni], 0, 0, 0);
    __syncthreads();
  }

  float* Cz = Tg + (size_t)z * 512 * TCOLS;
  const float* ex = RB + (size_t)z * 128;
#pragma unroll
  for (int mi = 0; mi < 4; ++mi) {
#pragma unroll
    for (int ni = 0; ni < 2; ++ni) {
#pragma unroll
      for (int r = 0; r < 4; ++r) {
        int gm = m0 + wm + mi * 16 + quad * 4 + r;
        int gn = n0 + wn + ni * 16 + mr;
        if (gn < TCOLS) Cz[(size_t)gm * TCOLS + gn] = acc[mi][ni][r] + ex[gn];
      }
    }
  }
}

// ---------------------------------------------------------------------------
// MEGA v2: grid 512, tile 32(q) x 16(k), 512 threads, LDS 48768 -> 2+ blk/CU.
// P[m][h] is packed DIRECTLY into the epilogue MFMA A-fragments (no Pl LDS):
// thread (w,quad,mr) owns rows m=w*64+mi*16+mr and columns h in
// [quad*8, quad*8+8) -- exactly the fragment it feeds to the pair projection.
// Per h: {issue T(h+1) global->reg} ; waves 0-1 S-MFMA -> Ssc ;
//        raw s_barrier (lgkm-only: T loads stay in flight) ;
//        lanes quad==h>>3 pack af from Ssc+T-LDS ; ds_write T(h+1) (dbuf, 84
//        stride = conflict-free) ; gload_lds QK(h+1) (single buffer) ;
//        __syncthreads (drains QK).
// LDS: Qs @0 (8192) | Ks @8192 (4096) | T dbuf @12288 (2x16128: Tq 32x84f,
//      Tk 16x84f @+2688f) | Ssc @44544 (32x17 f32) | fmL @46720 (2048).
// ---------------------------------------------------------------------------
#define MEGA_LDS 48768
__global__ __launch_bounds__(512) void mega_kernel(
    const bf16* __restrict__ QKp, const float* __restrict__ Tg,
    const short* __restrict__ fm_tab, const bf16* __restrict__ WpT,
    const float* __restrict__ b_pair, const float* __restrict__ yqk,
    float* __restrict__ out) {
  extern __shared__ char sm[];
  float* Ssc = (float*)(sm + 44544);
  short* fmL = (short*)(sm + 46720);

  const int t = threadIdx.x;
  const int lane = t & 63, w = t >> 6;
  const int quad = lane >> 4, mr = lane & 15;
  const int q0 = (blockIdx.x >> 5) * 32;   // 16 q-tiles
  const int k0 = (blockIdx.x & 31) * 16;   // 32 k-tiles

  // --- QK staging chunk constants (gload_lds, wave-uniform guards) ---
  const int qc_r = (t & 127) >> 2;
  const int qcol = (t >> 7) * 32 + (((t & 3) ^ (qc_r & 3)) * 8);
  const int kc_r = (t & 63) >> 2;                    // valid t<256
  const int kcol = ((t >> 6) & 3) * 32 + (((t & 3) ^ (kc_r & 3)) * 8);

  // --- T staging chunk constants (reg-staged: any mapping ok) ---
  const int tr1 = t / 20, to1 = (t % 20) * 4;         // rows 0..25 (Tq side)
  const int ti1 = tr1 * TLDS + to1;
  const int c2 = 512 + t;
  const int tr2 = c2 / 20, to2 = (c2 % 20) * 4;       // rows 25..47
  const int ti2 = (tr2 < 32) ? tr2 * TLDS + to2 : 2688 + (tr2 - 32) * TLDS + to2;
  const bool hasB = (t < 448);

  // ---- prologue: stage QK(0), fmL, T(0) ----
  {
    const float* sq_ = Tg;
    const float* sk_ = Tg + (size_t)32 * SPOOL * TCOLS;
    f32x4 pA = *(const f32x4*)(sq_ + (size_t)(q0 + tr1) * TCOLS + to1);
    f32x4 pB = (f32x4){0.f, 0.f, 0.f, 0.f};
    if (hasB) {
      const float* s2 = (tr2 < 32) ? sq_ + (size_t)(q0 + tr2) * TCOLS + to2
                                   : sk_ + (size_t)(k0 + tr2 - 32) * TCOLS + to2;
      pB = *(const f32x4*)s2;
    }
    gload_lds16(QKp + (size_t)(q0 + qc_r) * 8192 + qcol, sm + t * 16);
    if (t < 256)
      gload_lds16(QKp + (size_t)(k0 + kc_r) * 8192 + 4096 + kcol, sm + 8192 + t * 16);
    if (t < 128) gload_lds16(fm_tab + t * 8, (char*)fmL + t * 16);
    float* dT = (float*)(sm + 12288);  // buf 0
    *(f32x4*)&dT[ti1] = pA;
    if (hasB) *(f32x4*)&dT[ti2] = pB;
  }
  __syncthreads();

  // ---- hoist per-mi pack indices (m = w*64 + mi*16 + mr) ----
  int tqa[4], tqc[4], tka[4], tkc[4], ssco[4];
  float sgnv[4];
#pragma unroll
  for (int mi = 0; mi < 4; ++mi) {
    int m = w * 64 + mi * 16 + mr;
    int qL = m >> 4, kL = m & 15;
    int pq = 512 + (k0 + kL) - (q0 + qL);
    int gq = fmL[pq], gk = fmL[1024 - pq];
    sgnv[mi] = (pq > 512) ? 1.f : ((pq < 512) ? -1.f : 0.f);
    tqa[mi] = qL * TLDS + gq;
    tqc[mi] = qL * TLDS + 66;
    tka[mi] = 2688 + kL * TLDS + gk;
    tkc[mi] = 2688 + kL * TLDS + 66;
    ssco[mi] = qL * 17 + kL;
  }

  short8 af[4];  // epilogue A-fragments, filled column-by-column over h

  for (int hg = 0; hg < 4; ++hg) {
#pragma unroll
    for (int hj = 0; hj < 8; ++hj) {
      const int h = hg * 8 + hj;
      const bool notlast = (h < 31);
      // -- issue T(h+1) global->reg (in flight across the S phase) --
      f32x4 tA = (f32x4){0.f, 0.f, 0.f, 0.f}, tB = (f32x4){0.f, 0.f, 0.f, 0.f};
      if (notlast) {
        const float* sq_ = Tg + (size_t)(h + 1) * SPOOL * TCOLS;
        const float* sk_ = Tg + (size_t)(33 + h) * SPOOL * TCOLS;
        tA = *(const f32x4*)(sq_ + (size_t)(q0 + tr1) * TCOLS + to1);
        if (hasB) {
          const float* s2 = (tr2 < 32) ? sq_ + (size_t)(q0 + tr2) * TCOLS + to2
                                       : sk_ + (size_t)(k0 + tr2 - 32) * TCOLS + to2;
          tB = *(const f32x4*)s2;
        }
      }
      // -- phase S: waves 0-1 compute S(h) 32x16 --
      if (w < 2) {
        const short* Qb = (const short*)sm;
        const short* Kb = (const short*)(sm + 8192);
        const int ra = w * 16 + mr;
        f32x4 accS = (f32x4){0.f, 0.f, 0.f, 0.f};
#pragma unroll
        for (int ks = 0; ks < 4; ++ks) {
          short8 a = *(const short8*)&Qb[ks * 1024 + ra * 32 + ((quad ^ (ra & 3)) * 8)];
          short8 b = *(const short8*)&Kb[ks * 512 + mr * 32 + ((quad ^ (mr & 3)) * 8)];
          accS = __builtin_amdgcn_mfma_f32_16x16x32_bf16(a, b, accS, 0, 0, 0);
        }
#pragma unroll
        for (int r = 0; r < 4; ++r)
          Ssc[(w * 16 + quad * 4 + r) * 17 + mr] = accS[r];
      }
      // raw barrier: drain LDS only (T global loads stay in flight)
      asm volatile("s_waitcnt lgkmcnt(0)" ::: "memory");
      __builtin_amdgcn_s_barrier();
      __builtin_amdgcn_sched_barrier(0);
      // -- phase P: pack column h into af (quarter lanes) --
      if (quad == hg) {
        const float* Tl = (const float*)(sm + 12288 + (hj & 1) * 16128);
#pragma unroll
        for (int mi = 0; mi < 4; ++mi) {
          float s = sgnv[mi];
          float vq = Tl[tqa[mi]] + s * Tl[tqa[mi] + 33] + Tl[tqc[mi]];
          float vk = Tl[tka[mi]] - s * Tl[tka[mi] + 33] + Tl[tkc[mi]];
          float val = Ssc[ssco[mi]] + 0.5f * (vq + vk);
          af[mi][hj] = f2bs(val);
        }
      }
      // -- write T(h+1) to other buffer; stage QK(h+1) (single buffer) --
      if (notlast) {
        float* dT = (float*)(sm + 12288 + ((hj + 1) & 1) * 16128);
        *(f32x4*)&dT[ti1] = tA;
        if (hasB) *(f32x4*)&dT[ti2] = tB;
        gload_lds16(QKp + (size_t)(q0 + qc_r) * 8192 + (h + 1) * 128 + qcol,
                    sm + t * 16);
        if (t < 256)
          gload_lds16(QKp + (size_t)(k0 + kc_r) * 8192 + 4096 + (h + 1) * 128 + kcol,
                      sm + 8192 + t * 16);
      }
      __syncthreads();
    }
  }

  // ---- pair projection + epilogue (af already in registers) ----
  short8 bfr[8];
  float bp[8];
#pragma unroll
  for (int ni = 0; ni < 8; ++ni) {
    int c = ni * 16 + mr;
    bfr[ni] = *(const short8*)(WpT + (size_t)c * 32 + quad * 8);
    bp[ni] = b_pair[c];
  }
#pragma unroll
  for (int mi = 0; mi < 4; ++mi) {
    f32x4 acc[8];
#pragma unroll
    for (int ni = 0; ni < 8; ++ni)
      acc[ni] = __builtin_amdgcn_mfma_f32_16x16x32_bf16(
          af[mi], bfr[ni], (f32x4){0.f, 0.f, 0.f, 0.f}, 0, 0, 0);
#pragma unroll
    for (int r = 0; r < 4; ++r) {
      int m = w * 64 + mi * 16 + quad * 4 + r;
      int q = q0 + (m >> 4), k = k0 + (m & 15);
      const float* yq = yqk + (size_t)q * 256;
      const float* yk = yqk + (size_t)k * 256 + 128;
      float* orow = out + ((size_t)q * 512 + k) * 128;
#pragma unroll
      for (int ni = 0; ni < 8; ++ni) {
        int c = ni * 16 + mr;
        orow[c] = acc[ni][r] + bp[ni] + yq[c] + yk[c];
      }
    }
  }
}

// ===========================================================================
extern "C" void kernel_launch(void* const* d_in, const int* in_sizes, int n_in,
                              void* d_out, int out_size, void* d_ws, size_t ws_size,
                              hipStream_t stream) {
  const float* x      = (const float*)d_in[0];
  const float* w_rms  = (const float*)d_in[1];
  const float* W_q    = (const float*)d_in[2];
  const float* W_k    = (const float*)d_in[3];
  const float* W_pos  = (const float*)d_in[4];
  const float* b_pos  = (const float*)d_in[5];
  const float* qrb    = (const float*)d_in[6];
  const float* krb    = (const float*)d_in[7];
  const float* W_yq   = (const float*)d_in[8];
  const float* W_yk   = (const float*)d_in[9];
  const float* W_pair = (const float*)d_in[10];
  const float* b_pair = (const float*)d_in[11];
  float* out = (float*)d_out;

  static bool attr_set = false;
  if (!attr_set) {
    (void)hipFuncSetAttribute((const void*)mega_kernel,
                              hipFuncAttributeMaxDynamicSharedMemorySize, MEGA_LDS);
    attr_set = true;
  }

  // ---- workspace layout (~42 MB) ----
  char* w = (char*)d_ws;
  bf16* xn   = (bf16*)w; w += (size_t)SPOOL * DMODEL * 2;       // 1.5 MB
  bf16* xg   = (bf16*)w; w += (size_t)SPOOL * DMODEL * 2;       // 1.5 MB
  bf16* QKp  = (bf16*)w; w += (size_t)SPOOL * 8192 * 2;         // 8.4 MB (Q|K)
  float* yqk = (float*)w; w += (size_t)SPOOL * 256 * 4;         // 0.5 MB
  bf16* WpT  = (bf16*)w; w += (size_t)HDIM * NHEADS * 2;        // 8 KB
  float* SW0 = (float*)w; w += (size_t)33 * HDTOT * 4;          // 0.54 MB
  float* SW1 = (float*)w; w += (size_t)33 * HDTOT * 4;          // 0.54 MB
  bf16* SWb  = (bf16*)w; w += (size_t)NHEADS * 128 * 128 * 2;   // 1.05 MB
  float* RB  = (float*)w; w += (size_t)64 * 128 * 4;            // 32 KB
  short* fm_tab = (short*)w; w += 1024 * 2;                     // 2 KB
  w = (char*)(((uintptr_t)w + 255) & ~(uintptr_t)255);
  float* Tg = (float*)w; w += (size_t)2 * NHEADS * SPOOL * TCOLS * 4;  // 26.2 MB

  // 1. fused pool+rms+gelu (blocks 0..511) + suffix sums (512..527)
  pool_suffix<<<SPOOL + HDTOT / 256, 256, 0, stream>>>(x, w_rms, W_pos, xn, xg, SW0, SW1);
  // 2. prep tables (SWb, RB, fm, WpT)
  prep_kernel<<<98, 256, 0, stream>>>(SW0, SW1, b_pos, qrb, krb, W_pair,
                                      SWb, RB, fm_tab, WpT);
  // 3. merged projections: Q|K (bf16) + yq|yk (f32), W read directly (f32)
  gemm_proj32<<<dim3(264, 2), 256, 0, stream>>>(
      xn, xg, W_q, W_k, W_yq, W_yk, QKp, yqk);
  // 4. rel tables (both sides, z = side*32+h)
  gemm_table<<<dim3(128 / 64, SPOOL / 128, 64), 256, 0, stream>>>(QKp, SWb, RB, Tg);
  // 5. fused S + rel-lookup + reg-pack + pair projection + epilogue
  mega_kernel<<<512, 512, MEGA_LDS, stream>>>(QKp, Tg, fm_tab, WpT, b_pair, yqk, out);
}